// Round 11
// baseline (1269.504 us; speedup 1.0000x reference)
//
#include <hip/hip_runtime.h>

#define B_ 32
#define S_ 8
#define H_ 4096
#define HQ_ 32
#define HK_ 8
#define D_ 128
#define L_ 4096
#define KK 4096

typedef short s16x8 __attribute__((ext_vector_type(8)));
typedef float f32x4 __attribute__((ext_vector_type(4)));

// f32 -> bf16 bits, round-to-nearest-even (scalar; for non-pairable sites)
static __device__ __forceinline__ unsigned short f2bf(float x){
  unsigned int u = __builtin_bit_cast(unsigned int, x);
  u += 0x7fffu + ((u >> 16) & 1u);
  return (unsigned short)(u >> 16);
}

static __device__ __forceinline__ float bf2f(unsigned int h){
  unsigned int u = h << 16;
  return __builtin_bit_cast(float, u);
}

// HW packed convert: dst = {lo: cvt(a), hi: cvt(b)}, RNE (bit-identical to f2bf)
static __device__ __forceinline__ unsigned int pk2(float a, float b){
  unsigned int r;
  asm("v_cvt_pk_bf16_f32 %0, %1, %2" : "=v"(r) : "v"(a), "v"(b));
  return r;
}

static __device__ __forceinline__ s16x8 cvt8(f32x4 a, f32x4 b){
  uint4 d;
  d.x = pk2(a[0], a[1]);
  d.y = pk2(a[2], a[3]);
  d.z = pk2(b[0], b[1]);
  d.w = pk2(b[2], b[3]);
  return __builtin_bit_cast(s16x8, d);
}

// ---------------- fused QKV GEMM (BM=64, register-pipelined staging)
__global__ __launch_bounds__(256) void gemm_qkv(const float* __restrict__ A,
    const float* __restrict__ Wq, const float* __restrict__ Wk,
    const float* __restrict__ Wv, float* __restrict__ C)
{
  __shared__ short As[64][72];
  __shared__ short Bs[64][72];
  const int m0 = blockIdx.y * 64;
  const int n0 = blockIdx.x * 64;        // global col in [0,6144)
  const float* W; int nw;
  if (n0 < 4096){ W = Wq; nw = n0; }
  else if (n0 < 5120){ W = Wk; nw = n0 - 4096; }
  else { W = Wv; nw = n0 - 5120; }
  const int tid = threadIdx.x;
  const int lane = tid & 63;
  const int w = tid >> 6;
  const int c = lane & 15;
  const int g = lane >> 4;
  const int wm = (w & 1) * 32;
  const int wn = (w >> 1) * 32;
  const int srow = tid >> 3;
  const int skc  = tid & 7;

  const float* Ar0 = A + (m0 + srow) * KK + skc * 8;
  const float* Ar1 = Ar0 + 32 * KK;
  const float* Wr0 = W + (nw + srow) * KK + skc * 8;
  const float* Wr1 = Wr0 + 32 * KK;

  f32x4 acc00 = {0.f,0.f,0.f,0.f};
  f32x4 acc01 = acc00, acc10 = acc00, acc11 = acc00;

  // preload tile 0 into registers
  f32x4 x0 = *(const f32x4*)(Ar0);
  f32x4 x1 = *(const f32x4*)(Ar0 + 4);
  f32x4 x2 = *(const f32x4*)(Ar1);
  f32x4 x3 = *(const f32x4*)(Ar1 + 4);
  f32x4 y0 = *(const f32x4*)(Wr0);
  f32x4 y1 = *(const f32x4*)(Wr0 + 4);
  f32x4 y2 = *(const f32x4*)(Wr1);
  f32x4 y3 = *(const f32x4*)(Wr1 + 4);

  for (int kt = 0; kt < KK; kt += 64){
    __syncthreads();
    *(s16x8*)&As[srow][skc*8]    = cvt8(x0, x1);
    *(s16x8*)&As[srow+32][skc*8] = cvt8(x2, x3);
    *(s16x8*)&Bs[srow][skc*8]    = cvt8(y0, y1);
    *(s16x8*)&Bs[srow+32][skc*8] = cvt8(y2, y3);
    __syncthreads();
    // prefetch next tile (wraps on last iter; result unused)
    int ktn = (kt + 64) & (KK - 1);
    x0 = *(const f32x4*)(Ar0 + ktn);
    x1 = *(const f32x4*)(Ar0 + ktn + 4);
    x2 = *(const f32x4*)(Ar1 + ktn);
    x3 = *(const f32x4*)(Ar1 + ktn + 4);
    y0 = *(const f32x4*)(Wr0 + ktn);
    y1 = *(const f32x4*)(Wr0 + ktn + 4);
    y2 = *(const f32x4*)(Wr1 + ktn);
    y3 = *(const f32x4*)(Wr1 + ktn + 4);
#pragma unroll
    for (int kk = 0; kk < 2; ++kk){
      s16x8 a0 = *(const s16x8*)&As[wm + c][kk*32 + 8*g];
      s16x8 a1 = *(const s16x8*)&As[wm + 16 + c][kk*32 + 8*g];
      s16x8 b0 = *(const s16x8*)&Bs[wn + c][kk*32 + 8*g];
      s16x8 b1 = *(const s16x8*)&Bs[wn + 16 + c][kk*32 + 8*g];
      acc00 = __builtin_amdgcn_mfma_f32_16x16x32_bf16(a0, b0, acc00, 0, 0, 0);
      acc01 = __builtin_amdgcn_mfma_f32_16x16x32_bf16(a0, b1, acc01, 0, 0, 0);
      acc10 = __builtin_amdgcn_mfma_f32_16x16x32_bf16(a1, b0, acc10, 0, 0, 0);
      acc11 = __builtin_amdgcn_mfma_f32_16x16x32_bf16(a1, b1, acc11, 0, 0, 0);
    }
  }
#pragma unroll
  for (int r = 0; r < 4; ++r){
    int row0 = m0 + wm + 4*g + r;
    int row1 = row0 + 16;
    int col0 = n0 + wn + c;
    int col1 = col0 + 16;
    C[row0 * 6144 + col0] = acc00[r];
    C[row0 * 6144 + col1] = acc01[r];
    C[row1 * 6144 + col0] = acc10[r];
    C[row1 * 6144 + col1] = acc11[r];
  }
}

// ---------------- O-proj GEMM (BM=64, register-pipelined staging)
__global__ __launch_bounds__(256) void gemm_bt(const float* __restrict__ A,
    const float* __restrict__ W, float* __restrict__ C, int N)
{
  __shared__ short As[64][72];
  __shared__ short Bs[64][72];
  const int m0 = blockIdx.y * 64;
  const int n0 = blockIdx.x * 64;
  const int tid = threadIdx.x;
  const int lane = tid & 63;
  const int w = tid >> 6;
  const int c = lane & 15;
  const int g = lane >> 4;
  const int wm = (w & 1) * 32;
  const int wn = (w >> 1) * 32;
  const int srow = tid >> 3;
  const int skc  = tid & 7;

  const float* Ar0 = A + (m0 + srow) * KK + skc * 8;
  const float* Ar1 = Ar0 + 32 * KK;
  const float* Wr0 = W + (n0 + srow) * KK + skc * 8;
  const float* Wr1 = Wr0 + 32 * KK;

  f32x4 acc00 = {0.f,0.f,0.f,0.f};
  f32x4 acc01 = acc00, acc10 = acc00, acc11 = acc00;

  f32x4 x0 = *(const f32x4*)(Ar0);
  f32x4 x1 = *(const f32x4*)(Ar0 + 4);
  f32x4 x2 = *(const f32x4*)(Ar1);
  f32x4 x3 = *(const f32x4*)(Ar1 + 4);
  f32x4 y0 = *(const f32x4*)(Wr0);
  f32x4 y1 = *(const f32x4*)(Wr0 + 4);
  f32x4 y2 = *(const f32x4*)(Wr1);
  f32x4 y3 = *(const f32x4*)(Wr1 + 4);

  for (int kt = 0; kt < KK; kt += 64){
    __syncthreads();
    *(s16x8*)&As[srow][skc*8]    = cvt8(x0, x1);
    *(s16x8*)&As[srow+32][skc*8] = cvt8(x2, x3);
    *(s16x8*)&Bs[srow][skc*8]    = cvt8(y0, y1);
    *(s16x8*)&Bs[srow+32][skc*8] = cvt8(y2, y3);
    __syncthreads();
    int ktn = (kt + 64) & (KK - 1);
    x0 = *(const f32x4*)(Ar0 + ktn);
    x1 = *(const f32x4*)(Ar0 + ktn + 4);
    x2 = *(const f32x4*)(Ar1 + ktn);
    x3 = *(const f32x4*)(Ar1 + ktn + 4);
    y0 = *(const f32x4*)(Wr0 + ktn);
    y1 = *(const f32x4*)(Wr0 + ktn + 4);
    y2 = *(const f32x4*)(Wr1 + ktn);
    y3 = *(const f32x4*)(Wr1 + ktn + 4);
#pragma unroll
    for (int kk = 0; kk < 2; ++kk){
      s16x8 a0 = *(const s16x8*)&As[wm + c][kk*32 + 8*g];
      s16x8 a1 = *(const s16x8*)&As[wm + 16 + c][kk*32 + 8*g];
      s16x8 b0 = *(const s16x8*)&Bs[wn + c][kk*32 + 8*g];
      s16x8 b1 = *(const s16x8*)&Bs[wn + 16 + c][kk*32 + 8*g];
      acc00 = __builtin_amdgcn_mfma_f32_16x16x32_bf16(a0, b0, acc00, 0, 0, 0);
      acc01 = __builtin_amdgcn_mfma_f32_16x16x32_bf16(a0, b1, acc01, 0, 0, 0);
      acc10 = __builtin_amdgcn_mfma_f32_16x16x32_bf16(a1, b0, acc10, 0, 0, 0);
      acc11 = __builtin_amdgcn_mfma_f32_16x16x32_bf16(a1, b1, acc11, 0, 0, 0);
    }
  }
#pragma unroll
  for (int r = 0; r < 4; ++r){
    int row0 = m0 + wm + 4*g + r;
    int row1 = row0 + 16;
    int col0 = n0 + wn + c;
    int col1 = col0 + 16;
    C[row0 * N + col0] = acc00[r];
    C[row0 * N + col1] = acc01[r];
    C[row1 * N + col0] = acc10[r];
    C[row1 * N + col1] = acc11[r];
  }
}

// ---------------- RoPE: q -> bf16 qb; k -> roped fp32 wskr; v -> compact wsvc
__global__ __launch_bounds__(256) void rope_prep(
    const float* __restrict__ qkv, const float* __restrict__ rope,
    unsigned short* __restrict__ qbuf, float* __restrict__ wskr, float* __restrict__ wsvc)
{
  const int bs = blockIdx.x;            // b*8+s
  const int tid = threadIdx.x;
  const float* cosv = rope + bs * 128;
  const float* sinv = cosv + 64;
  const float* row = qkv + bs * 6144;
#pragma unroll
  for (int it = 0; it < 16; ++it){
    int e = tid + it * 256;             // over HQ*D = 4096
    int d = e & 127; int dh = d & 63;
    float x  = row[e];
    float xp = row[e ^ 64];
    float o = (d < 64) ? (x * cosv[dh] - xp * sinv[dh]) : (x * cosv[dh] + xp * sinv[dh]);
    qbuf[bs*4096 + e] = f2bf(o);
  }
#pragma unroll
  for (int it = 0; it < 4; ++it){
    int e = tid + it * 256;             // over HK*D = 1024
    int d = e & 127; int dh = d & 63;
    float x  = row[4096 + e];
    float xp = row[4096 + (e ^ 64)];
    float o = (d < 64) ? (x * cosv[dh] - xp * sinv[dh]) : (x * cosv[dh] + xp * sinv[dh]);
    wskr[bs*1024 + e] = o;
    wsvc[bs*1024 + e] = row[5120 + e];
  }
}

// ---------------- per-chunk attention+copy body.
// FAST: chunk fully below ctx and contains no new rows.
// ALL copy stores on the attention path are PLAIN (partial-line NT stores
// defeat L2 write-merging -- validated R9: V NT->plain was -47us).
template<bool FAST>
static __device__ __forceinline__ void attn_chunk(
    int l0, int ctx, int pos,
    const float* __restrict__ Kpast, const float* __restrict__ Vpast,
    const float* __restrict__ KnewB, const float* __restrict__ VnewB,
    float* __restrict__ Kout, float* __restrict__ Vout,
    const s16x8 (&qf)[2][4], f32x4 (&accO)[2][8],
    float (&m_j)[2], float (&s_j)[2],
    int c, int g)
{
  const float scale = 0.08838834764831845f;  // 1/sqrt(128)
  f32x4 zero4 = {0.f,0.f,0.f,0.f};

  // K fragments + inline copy (touch once, in registers); plain stores.
  s16x8 kf[2][4];
#pragma unroll
  for (int i = 0; i < 2; ++i){
    int row = l0 + i*16 + c;
    const float* src;
    if (FAST){
      src = Kpast + row*1024 + 8*g;
    } else {
      bool kn = ((unsigned)(row - pos)) < 8u;
      src = (kn ? KnewB : Kpast) + row*1024 + 8*g;
    }
    float* dst = Kout + row*1024 + 8*g;
#pragma unroll
    for (int ks = 0; ks < 4; ++ks){
      f32x4 x = *(const f32x4*)(src + ks*32);
      f32x4 y = *(const f32x4*)(src + ks*32 + 4);
      *(f32x4*)(dst + ks*32) = x;
      *(f32x4*)(dst + ks*32 + 4) = y;
      kf[i][ks] = cvt8(x, y);
    }
  }
  // scores: D[l][q] = K * Q^T
  f32x4 sc[2][2];
#pragma unroll
  for (int i = 0; i < 2; ++i)
#pragma unroll
    for (int j = 0; j < 2; ++j) sc[i][j] = zero4;
#pragma unroll
  for (int ks = 0; ks < 4; ++ks)
#pragma unroll
    for (int i = 0; i < 2; ++i)
#pragma unroll
      for (int j = 0; j < 2; ++j)
        sc[i][j] = __builtin_amdgcn_mfma_f32_16x16x32_bf16(kf[i][ks], qf[j][ks], sc[i][j], 0, 0, 0);

  // online softmax (per q column = lane c, tile j)
  float p[2][2][4];
  float fj[2];
#pragma unroll
  for (int j = 0; j < 2; ++j){
    const int qpos = ctx + ((j*16 + c) & 7);
    float mx = -1e30f;
#pragma unroll
    for (int i = 0; i < 2; ++i)
#pragma unroll
      for (int r = 0; r < 4; ++r){
        float v;
        if (FAST){
          v = sc[i][j][r] * scale;
        } else {
          int lg = l0 + i*16 + 4*g + r;
          v = (lg <= qpos) ? sc[i][j][r] * scale : -1e30f;
        }
        p[i][j][r] = v;
        mx = fmaxf(mx, v);
      }
    mx = fmaxf(mx, __shfl_xor(mx, 16));
    mx = fmaxf(mx, __shfl_xor(mx, 32));
    float mnew = fmaxf(m_j[j], mx);
    float f = __expf(m_j[j] - mnew);
    float lsum = 0.f;
#pragma unroll
    for (int i = 0; i < 2; ++i)
#pragma unroll
      for (int r = 0; r < 4; ++r){
        float pv;
        if (FAST){
          pv = __expf(p[i][j][r] - mnew);
        } else {
          int lg = l0 + i*16 + 4*g + r;
          pv = (lg <= qpos) ? __expf(p[i][j][r] - mnew) : 0.f;
        }
        p[i][j][r] = pv;
        lsum += pv;
      }
    s_j[j] = s_j[j] * f + lsum;
    m_j[j] = mnew;
    fj[j] = f;
  }
  // rescale O accumulators
#pragma unroll
  for (int iq = 0; iq < 2; ++iq)
#pragma unroll
    for (int r = 0; r < 4; ++r){
      float fo = __shfl(fj[iq], 4*g + r);
#pragma unroll
      for (int t = 0; t < 8; ++t) accO[iq][t][r] *= fo;
    }
  // relayout P into PV A-fragments: lane needs P[l=8g..8g+7][q=iq*16+c]
  s16x8 pf[2];
#pragma unroll
  for (int iq = 0; iq < 2; ++iq){
    int pd00 = (int)pk2(p[0][iq][0], p[0][iq][1]);
    int pd01 = (int)pk2(p[0][iq][2], p[0][iq][3]);
    int pd10 = (int)pk2(p[1][iq][0], p[1][iq][1]);
    int pd11 = (int)pk2(p[1][iq][2], p[1][iq][3]);
    int sA = (((2*g) & 3) << 4) | c;
    int sB = (((2*g + 1) & 3) << 4) | c;
    int h = g >> 1;
    int t0a = __shfl(pd00, sA), t1a = __shfl(pd10, sA);
    int t0b = __shfl(pd01, sA), t1b = __shfl(pd11, sA);
    int t0c = __shfl(pd00, sB), t1c = __shfl(pd10, sB);
    int t0d = __shfl(pd01, sB), t1d = __shfl(pd11, sB);
    int4 dw;
    dw.x = h ? t1a : t0a;
    dw.y = h ? t1b : t0b;
    dw.z = h ? t1c : t0c;
    dw.w = h ? t1d : t0d;
    pf[iq] = __builtin_bit_cast(s16x8, dw);
  }
  // V: fragment loads (+ element-wise copy to cache, PLAIN stores) + PV MFMA
#pragma unroll
  for (int t = 0; t < 8; ++t){
    const int co = t*16 + c;
    float vv[8];
#pragma unroll
    for (int jj = 0; jj < 8; ++jj){
      int row = l0 + 8*g + jj;
      float x;
      if (FAST){
        x = Vpast[row*1024 + co];
      } else {
        bool kn = ((unsigned)(row - pos)) < 8u;
        x = *((kn ? VnewB : Vpast) + row*1024 + co);
      }
      Vout[row*1024 + co] = x;          // plain store: L2 merges 64B granules
      vv[jj] = x;
    }
    f32x4 va, vb;
    va[0] = vv[0]; va[1] = vv[1]; va[2] = vv[2]; va[3] = vv[3];
    vb[0] = vv[4]; vb[1] = vv[5]; vb[2] = vv[6]; vb[3] = vv[7];
    s16x8 vf = cvt8(va, vb);
    accO[0][t] = __builtin_amdgcn_mfma_f32_16x16x32_bf16(pf[0], vf, accO[0][t], 0, 0, 0);
    accO[1][t] = __builtin_amdgcn_mfma_f32_16x16x32_bf16(pf[1], vf, accO[1][t], 0, 0, 0);
  }
}

// ---------------- fused cache-copy + flash attention, fine-grained blocks.
// grid: b*64 + hk*8 + sp (2048 blocks, 128 threads = 2 waves).
__global__ __launch_bounds__(128) void copy_attn(
    const float* __restrict__ past, const float* __restrict__ wskr,
    const float* __restrict__ wsvc, const unsigned short* __restrict__ qb,
    const int* __restrict__ ctxlen, const int* __restrict__ startv,
    float* __restrict__ cache,
    unsigned short* __restrict__ pO, float* __restrict__ pM, float* __restrict__ pS)
{
  const int bid = blockIdx.x;
  const int sp = bid & 7;
  const int hk = (bid >> 3) & 7;
  const int b  = bid >> 6;
  const int tid = threadIdx.x;
  const int w = tid >> 6;                // 0..1
  const int lane = tid & 63;
  const int c = lane & 15;
  const int g = lane >> 4;
  const int ctx = ctxlen[b];
  const int pos = startv[b];
  const int lbase = sp * 512;
  const int pid = bid * 2 + w;

  const float* Kpast = past + (size_t)b * 4194304 + hk * 128;
  const float* Vpast = Kpast + 134217728;
  float* Kout = cache + (size_t)b * 4194304 + hk * 128;
  float* Vout = Kout + 134217728;
  const float* KnewB = wskr + b * 8192 + hk * 128 - pos * 1024;
  const float* VnewB = wsvc + b * 8192 + hk * 128 - pos * 1024;

  // attention chunks in this 512-row slice
  int attLim = 0;
  {
    int t1 = ctx + 7 - lbase;
    if (t1 >= 0){ attLim = (t1 >> 5) + 1; if (attLim > 16) attLim = 16; }
  }

  f32x4 zero4 = {0.f,0.f,0.f,0.f};
  float m_j[2] = {-1e30f, -1e30f};
  float s_j[2] = {0.f, 0.f};

  const int rr = lane >> 5;
  const int fq = lane & 31;

  if (attLim > w){
    // Q fragments (B-operand): qf[jtile][kstep]
    s16x8 qf[2][4];
#pragma unroll
    for (int j = 0; j < 2; ++j){
      int r = j*16 + c; int s = r & 7; int gh = r >> 3;
      const unsigned short* qp = qb + (((b*8 + s) * 32) + hk*4 + gh) * 128 + 8*g;
#pragma unroll
      for (int ks = 0; ks < 4; ++ks)
        qf[j][ks] = __builtin_bit_cast(s16x8, *(const uint4*)(qp + ks*32));
    }

    f32x4 accO[2][8];
#pragma unroll
    for (int i = 0; i < 2; ++i)
#pragma unroll
      for (int t = 0; t < 8; ++t) accO[i][t] = zero4;

    for (int ci = w; ci < attLim; ci += 2){
      const int l0 = lbase + ci * 32;
      bool fullValid = (l0 + 31 <= ctx);
      bool hasNew = (l0 <= pos + 7) && (l0 + 31 >= pos);
      if (fullValid && !hasNew)
        attn_chunk<true >(l0, ctx, pos, Kpast, Vpast, KnewB, VnewB, Kout, Vout,
                          qf, accO, m_j, s_j, c, g);
      else
        attn_chunk<false>(l0, ctx, pos, Kpast, Vpast, KnewB, VnewB, Kout, Vout,
                          qf, accO, m_j, s_j, c, g);
    }
    // pO written only by waves that had chunks (bf16 partials)
#pragma unroll
    for (int iq = 0; iq < 2; ++iq)
#pragma unroll
      for (int t = 0; t < 8; ++t)
#pragma unroll
        for (int r = 0; r < 4; ++r)
          pO[(pid*32 + iq*16 + 4*g + r) * 128 + t*16 + c] = f2bf(accO[iq][t][r]);
  }

  // copy-only chunks (full-line streams: nontemporal both ways)
  int st2 = attLim + ((w - attLim) & 1);
  for (int ci = st2; ci < 16; ci += 2){
    const int l0 = lbase + ci * 32;
    bool inter = (l0 <= pos + 7) && (l0 + 31 >= pos);
    if (!inter){
#pragma unroll
      for (int j = 0; j < 16; ++j){
        int row = l0 + rr + 2*j;
        f32x4 kv = __builtin_nontemporal_load((const f32x4*)(Kpast + row*1024) + fq);
        f32x4 vv = __builtin_nontemporal_load((const f32x4*)(Vpast + row*1024) + fq);
        __builtin_nontemporal_store(kv, (f32x4*)(Kout + row*1024) + fq);
        __builtin_nontemporal_store(vv, (f32x4*)(Vout + row*1024) + fq);
      }
    } else {
      for (int j = 0; j < 16; ++j){
        int row = l0 + rr + 2*j;
        bool kn = ((unsigned)(row - pos)) < 8u;
        f32x4 kv = __builtin_nontemporal_load((const f32x4*)((kn ? KnewB : Kpast) + row*1024) + fq);
        f32x4 vv = __builtin_nontemporal_load((const f32x4*)((kn ? VnewB : Vpast) + row*1024) + fq);
        __builtin_nontemporal_store(kv, (f32x4*)(Kout + row*1024) + fq);
        __builtin_nontemporal_store(vv, (f32x4*)(Vout + row*1024) + fq);
      }
    }
  }

  // pM/pS always written (merge uses pS==0 to skip empty partials)
#pragma unroll
  for (int j = 0; j < 2; ++j){
    float sj = s_j[j];
    sj += __shfl_xor(sj, 16);
    sj += __shfl_xor(sj, 32);
    if (g == 0){
      pM[pid*32 + j*16 + c] = m_j[j];
      pS[pid*32 + j*16 + c] = sj;
    }
  }
}

// ---------------- merge 16 partials per (b,hk), skipping empty ones (bf16 pO)
__global__ __launch_bounds__(256) void merge_attn(const unsigned short* __restrict__ pO,
    const float* __restrict__ pM, const float* __restrict__ pS, float* __restrict__ attn)
{
  const int bh = blockIdx.x;             // b*8+hk
  const int b = bh >> 3, hk = bh & 7;
  const int tid = threadIdx.x;
  const int q = tid >> 3;                // 0..31
  const int d0 = (tid & 7) * 16;
  const int base = bh * 16;
  float eP[16], sv[16];
  float M = -1e30f;
#pragma unroll
  for (int p2 = 0; p2 < 16; ++p2){
    float m = pM[(base + p2) * 32 + q];
    eP[p2] = m;
    M = fmaxf(M, m);
  }
  float den = 0.f;
#pragma unroll
  for (int p2 = 0; p2 < 16; ++p2){
    float s_ = pS[(base + p2) * 32 + q];
    sv[p2] = s_;
    float e = __expf(eP[p2] - M);
    eP[p2] = e;
    den += e * s_;
  }
  float inv = 1.f / den;
  float a[16];
#pragma unroll
  for (int k2 = 0; k2 < 16; ++k2) a[k2] = 0.f;
#pragma unroll
  for (int p2 = 0; p2 < 16; ++p2){
    if (sv[p2] != 0.f){
      const unsigned short* src = pO + ((base + p2) * 32 + q) * 128 + d0;
      float e = eP[p2];
      uint4 w0 = *(const uint4*)(src);      // 8 bf16
      uint4 w1 = *(const uint4*)(src + 8);  // 8 bf16
      unsigned int wd[8] = {w0.x, w0.y, w0.z, w0.w, w1.x, w1.y, w1.z, w1.w};
#pragma unroll
      for (int k2 = 0; k2 < 8; ++k2){
        a[2*k2]   += e * bf2f(wd[k2] & 0xffffu);
        a[2*k2+1] += e * bf2f(wd[k2] >> 16);
      }
    }
  }
  const int gh = q >> 3, s = q & 7;
  float* o = attn + (b*8 + s) * 4096 + (hk*4 + gh) * 128 + d0;
#pragma unroll
  for (int k2 = 0; k2 < 16; ++k2) o[k2] = a[k2] * inv;
}

extern "C" void kernel_launch(void* const* d_in, const int* in_sizes, int n_in,
                              void* d_out, int out_size, void* d_ws, size_t ws_size,
                              hipStream_t stream) {
  const float* hidden = (const float*)d_in[0];
  const float* past   = (const float*)d_in[1];
  const float* rope   = (const float*)d_in[2];
  const int*   ctx    = (const int*)d_in[3];
  const int*   start  = (const int*)d_in[4];
  const float* Wq     = (const float*)d_in[5];
  const float* Wk     = (const float*)d_in[6];
  const float* Wv     = (const float*)d_in[7];
  const float* Wo     = (const float*)d_in[8];

  float* out_attn  = (float*)d_out;                 // (B,S,H) = 1048576 floats
  float* out_cache = out_attn + 1048576;            // (2,B,L,HK,D)

  float* ws = (float*)d_ws;
  float* qkv    = ws;                               // 256 x 6144 = 1572864
  float* wsattn = ws + 1572864;                     // 1048576 (written by merge)
  float* wskr   = wsattn;                           // aliased; dead before merge writes
  float* wsvc   = wsattn + 262144;                  // aliased; dead before merge writes
  unsigned short* qb = (unsigned short*)(ws + 2621440); // 1048576 bf16
  unsigned short* pO = (unsigned short*)(ws + 3145728); // 4096 partials * 32 * 128 bf16
  float* pM = ws + 19922944;                        // 4096 * 32
  float* pS = ws + 20054016;                        // 4096 * 32

  // fused QKV projection (bf16 MFMA, fp32 accum), BM=64, reg-pipelined
  gemm_qkv<<<dim3(96, 4), 256, 0, stream>>>(hidden, Wq, Wk, Wv, qkv);

  // rope q (-> bf16) and k (-> fp32), compact v
  rope_prep<<<256, 256, 0, stream>>>(qkv, rope, qb, wskr, wsvc);

  // fused cache copy + flash-decode attention, 2048 x 128-thread blocks
  copy_attn<<<2048, 128, 0, stream>>>(past, wskr, wsvc, qb, ctx, start,
                                      out_cache, pO, pM, pS);
  merge_attn<<<B_ * HK_, 256, 0, stream>>>(pO, pM, pS, wsattn);

  // output projection, BM=64, reg-pipelined
  gemm_bt<<<dim3(64, 4), 256, 0, stream>>>(wsattn, Wo, out_attn, 4096);
}

// Round 12
// 585.468 us; speedup vs baseline: 2.1684x; 2.1684x over previous
//
#include <hip/hip_runtime.h>

#define B_ 32
#define S_ 8
#define H_ 4096
#define HQ_ 32
#define HK_ 8
#define D_ 128
#define L_ 4096
#define KK 4096
#define KHALF 2048

typedef short s16x8 __attribute__((ext_vector_type(8)));
typedef float f32x4 __attribute__((ext_vector_type(4)));

// f32 -> bf16 bits, round-to-nearest-even (integer ALU; do NOT use inline-asm
// cvt_pk here -- R11: asm in the load chain breaks pipelining, 2x slowdown)
static __device__ __forceinline__ unsigned short f2bf(float x){
  unsigned int u = __builtin_bit_cast(unsigned int, x);
  u += 0x7fffu + ((u >> 16) & 1u);
  return (unsigned short)(u >> 16);
}

static __device__ __forceinline__ float bf2f(unsigned int h){
  unsigned int u = h << 16;
  return __builtin_bit_cast(float, u);
}

static __device__ __forceinline__ s16x8 cvt8(f32x4 a, f32x4 b){
  s16x8 r;
  r[0]=(short)f2bf(a[0]); r[1]=(short)f2bf(a[1]); r[2]=(short)f2bf(a[2]); r[3]=(short)f2bf(a[3]);
  r[4]=(short)f2bf(b[0]); r[5]=(short)f2bf(b[1]); r[6]=(short)f2bf(b[2]); r[7]=(short)f2bf(b[3]);
  return r;
}

// ---------------- fused QKV GEMM (BM=64, reg-pipelined, split-K x2)
// grid (96, 4, 2); z picks K-half; partials summed in rope_prep.
__global__ __launch_bounds__(256) void gemm_qkv(const float* __restrict__ A,
    const float* __restrict__ Wq, const float* __restrict__ Wk,
    const float* __restrict__ Wv, float* __restrict__ C)
{
  __shared__ short As[64][72];
  __shared__ short Bs[64][72];
  const int m0 = blockIdx.y * 64;
  const int n0 = blockIdx.x * 64;        // global col in [0,6144)
  const int k0 = blockIdx.z * KHALF;
  float* Cz = C + blockIdx.z * 1572864;
  const float* W; int nw;
  if (n0 < 4096){ W = Wq; nw = n0; }
  else if (n0 < 5120){ W = Wk; nw = n0 - 4096; }
  else { W = Wv; nw = n0 - 5120; }
  const int tid = threadIdx.x;
  const int lane = tid & 63;
  const int w = tid >> 6;
  const int c = lane & 15;
  const int g = lane >> 4;
  const int wm = (w & 1) * 32;
  const int wn = (w >> 1) * 32;
  const int srow = tid >> 3;
  const int skc  = tid & 7;

  const float* Ar0 = A + (m0 + srow) * KK + skc * 8 + k0;
  const float* Ar1 = Ar0 + 32 * KK;
  const float* Wr0 = W + (nw + srow) * KK + skc * 8 + k0;
  const float* Wr1 = Wr0 + 32 * KK;

  f32x4 acc00 = {0.f,0.f,0.f,0.f};
  f32x4 acc01 = acc00, acc10 = acc00, acc11 = acc00;

  // preload tile 0 into registers
  f32x4 x0 = *(const f32x4*)(Ar0);
  f32x4 x1 = *(const f32x4*)(Ar0 + 4);
  f32x4 x2 = *(const f32x4*)(Ar1);
  f32x4 x3 = *(const f32x4*)(Ar1 + 4);
  f32x4 y0 = *(const f32x4*)(Wr0);
  f32x4 y1 = *(const f32x4*)(Wr0 + 4);
  f32x4 y2 = *(const f32x4*)(Wr1);
  f32x4 y3 = *(const f32x4*)(Wr1 + 4);

  for (int kt = 0; kt < KHALF; kt += 64){
    __syncthreads();
    *(s16x8*)&As[srow][skc*8]    = cvt8(x0, x1);
    *(s16x8*)&As[srow+32][skc*8] = cvt8(x2, x3);
    *(s16x8*)&Bs[srow][skc*8]    = cvt8(y0, y1);
    *(s16x8*)&Bs[srow+32][skc*8] = cvt8(y2, y3);
    __syncthreads();
    // prefetch next tile (wraps on last iter; result unused)
    int ktn = (kt + 64) & (KHALF - 1);
    x0 = *(const f32x4*)(Ar0 + ktn);
    x1 = *(const f32x4*)(Ar0 + ktn + 4);
    x2 = *(const f32x4*)(Ar1 + ktn);
    x3 = *(const f32x4*)(Ar1 + ktn + 4);
    y0 = *(const f32x4*)(Wr0 + ktn);
    y1 = *(const f32x4*)(Wr0 + ktn + 4);
    y2 = *(const f32x4*)(Wr1 + ktn);
    y3 = *(const f32x4*)(Wr1 + ktn + 4);
#pragma unroll
    for (int kk = 0; kk < 2; ++kk){
      s16x8 a0 = *(const s16x8*)&As[wm + c][kk*32 + 8*g];
      s16x8 a1 = *(const s16x8*)&As[wm + 16 + c][kk*32 + 8*g];
      s16x8 b0 = *(const s16x8*)&Bs[wn + c][kk*32 + 8*g];
      s16x8 b1 = *(const s16x8*)&Bs[wn + 16 + c][kk*32 + 8*g];
      acc00 = __builtin_amdgcn_mfma_f32_16x16x32_bf16(a0, b0, acc00, 0, 0, 0);
      acc01 = __builtin_amdgcn_mfma_f32_16x16x32_bf16(a0, b1, acc01, 0, 0, 0);
      acc10 = __builtin_amdgcn_mfma_f32_16x16x32_bf16(a1, b0, acc10, 0, 0, 0);
      acc11 = __builtin_amdgcn_mfma_f32_16x16x32_bf16(a1, b1, acc11, 0, 0, 0);
    }
  }
#pragma unroll
  for (int r = 0; r < 4; ++r){
    int row0 = m0 + wm + 4*g + r;
    int row1 = row0 + 16;
    int col0 = n0 + wn + c;
    int col1 = col0 + 16;
    Cz[row0 * 6144 + col0] = acc00[r];
    Cz[row0 * 6144 + col1] = acc01[r];
    Cz[row1 * 6144 + col0] = acc10[r];
    Cz[row1 * 6144 + col1] = acc11[r];
  }
}

// ---------------- O-proj GEMM (BM=64, reg-pipelined, split-K x2)
// grid (64, 4, 2); partials summed by add2.
__global__ __launch_bounds__(256) void gemm_bt(const float* __restrict__ A,
    const float* __restrict__ W, float* __restrict__ C, int N)
{
  __shared__ short As[64][72];
  __shared__ short Bs[64][72];
  const int m0 = blockIdx.y * 64;
  const int n0 = blockIdx.x * 64;
  const int k0 = blockIdx.z * KHALF;
  float* Cz = C + blockIdx.z * 1048576;
  const int tid = threadIdx.x;
  const int lane = tid & 63;
  const int w = tid >> 6;
  const int c = lane & 15;
  const int g = lane >> 4;
  const int wm = (w & 1) * 32;
  const int wn = (w >> 1) * 32;
  const int srow = tid >> 3;
  const int skc  = tid & 7;

  const float* Ar0 = A + (m0 + srow) * KK + skc * 8 + k0;
  const float* Ar1 = Ar0 + 32 * KK;
  const float* Wr0 = W + (n0 + srow) * KK + skc * 8 + k0;
  const float* Wr1 = Wr0 + 32 * KK;

  f32x4 acc00 = {0.f,0.f,0.f,0.f};
  f32x4 acc01 = acc00, acc10 = acc00, acc11 = acc00;

  f32x4 x0 = *(const f32x4*)(Ar0);
  f32x4 x1 = *(const f32x4*)(Ar0 + 4);
  f32x4 x2 = *(const f32x4*)(Ar1);
  f32x4 x3 = *(const f32x4*)(Ar1 + 4);
  f32x4 y0 = *(const f32x4*)(Wr0);
  f32x4 y1 = *(const f32x4*)(Wr0 + 4);
  f32x4 y2 = *(const f32x4*)(Wr1);
  f32x4 y3 = *(const f32x4*)(Wr1 + 4);

  for (int kt = 0; kt < KHALF; kt += 64){
    __syncthreads();
    *(s16x8*)&As[srow][skc*8]    = cvt8(x0, x1);
    *(s16x8*)&As[srow+32][skc*8] = cvt8(x2, x3);
    *(s16x8*)&Bs[srow][skc*8]    = cvt8(y0, y1);
    *(s16x8*)&Bs[srow+32][skc*8] = cvt8(y2, y3);
    __syncthreads();
    int ktn = (kt + 64) & (KHALF - 1);
    x0 = *(const f32x4*)(Ar0 + ktn);
    x1 = *(const f32x4*)(Ar0 + ktn + 4);
    x2 = *(const f32x4*)(Ar1 + ktn);
    x3 = *(const f32x4*)(Ar1 + ktn + 4);
    y0 = *(const f32x4*)(Wr0 + ktn);
    y1 = *(const f32x4*)(Wr0 + ktn + 4);
    y2 = *(const f32x4*)(Wr1 + ktn);
    y3 = *(const f32x4*)(Wr1 + ktn + 4);
#pragma unroll
    for (int kk = 0; kk < 2; ++kk){
      s16x8 a0 = *(const s16x8*)&As[wm + c][kk*32 + 8*g];
      s16x8 a1 = *(const s16x8*)&As[wm + 16 + c][kk*32 + 8*g];
      s16x8 b0 = *(const s16x8*)&Bs[wn + c][kk*32 + 8*g];
      s16x8 b1 = *(const s16x8*)&Bs[wn + 16 + c][kk*32 + 8*g];
      acc00 = __builtin_amdgcn_mfma_f32_16x16x32_bf16(a0, b0, acc00, 0, 0, 0);
      acc01 = __builtin_amdgcn_mfma_f32_16x16x32_bf16(a0, b1, acc01, 0, 0, 0);
      acc10 = __builtin_amdgcn_mfma_f32_16x16x32_bf16(a1, b0, acc10, 0, 0, 0);
      acc11 = __builtin_amdgcn_mfma_f32_16x16x32_bf16(a1, b1, acc11, 0, 0, 0);
    }
  }
#pragma unroll
  for (int r = 0; r < 4; ++r){
    int row0 = m0 + wm + 4*g + r;
    int row1 = row0 + 16;
    int col0 = n0 + wn + c;
    int col1 = col0 + 16;
    Cz[row0 * N + col0] = acc00[r];
    Cz[row0 * N + col1] = acc01[r];
    Cz[row1 * N + col0] = acc10[r];
    Cz[row1 * N + col1] = acc11[r];
  }
}

// ---------------- sum two split-K partials into d_out
__global__ __launch_bounds__(256) void add2(const f32x4* __restrict__ a,
    const f32x4* __restrict__ b, f32x4* __restrict__ o)
{
  int i = blockIdx.x * 256 + threadIdx.x;   // 262144 f32x4 total, grid 1024
  o[i] = a[i] + b[i];
}

// ---------------- RoPE: sums split-K qkv halves; q -> bf16 qb; k -> wskr; v -> wsvc
__global__ __launch_bounds__(256) void rope_prep(
    const float* __restrict__ qkv0, const float* __restrict__ qkv1,
    const float* __restrict__ rope,
    unsigned short* __restrict__ qbuf, float* __restrict__ wskr, float* __restrict__ wsvc)
{
  const int bs = blockIdx.x;            // b*8+s
  const int tid = threadIdx.x;
  const float* cosv = rope + bs * 128;
  const float* sinv = cosv + 64;
  const float* row0 = qkv0 + bs * 6144;
  const float* row1 = qkv1 + bs * 6144;
#pragma unroll
  for (int it = 0; it < 16; ++it){
    int e = tid + it * 256;             // over HQ*D = 4096
    int d = e & 127; int dh = d & 63;
    float x  = row0[e] + row1[e];
    float xp = row0[e ^ 64] + row1[e ^ 64];
    float o = (d < 64) ? (x * cosv[dh] - xp * sinv[dh]) : (x * cosv[dh] + xp * sinv[dh]);
    qbuf[bs*4096 + e] = f2bf(o);
  }
#pragma unroll
  for (int it = 0; it < 4; ++it){
    int e = tid + it * 256;             // over HK*D = 1024
    int d = e & 127; int dh = d & 63;
    float x  = row0[4096 + e] + row1[4096 + e];
    float xp = row0[4096 + (e ^ 64)] + row1[4096 + (e ^ 64)];
    float o = (d < 64) ? (x * cosv[dh] - xp * sinv[dh]) : (x * cosv[dh] + xp * sinv[dh]);
    wskr[bs*1024 + e] = o;
    wsvc[bs*1024 + e] = row0[5120 + e] + row1[5120 + e];
  }
}

// ---------------- per-chunk attention+copy body.
// FAST: chunk fully below ctx and contains no new rows.
// ALL copy stores on the attention path are PLAIN (partial-line NT stores
// defeat L2 write-merging -- validated R9: V NT->plain was -47us).
template<bool FAST>
static __device__ __forceinline__ void attn_chunk(
    int l0, int ctx, int pos,
    const float* __restrict__ Kpast, const float* __restrict__ Vpast,
    const float* __restrict__ KnewB, const float* __restrict__ VnewB,
    float* __restrict__ Kout, float* __restrict__ Vout,
    const s16x8 (&qf)[2][4], f32x4 (&accO)[2][8],
    float (&m_j)[2], float (&s_j)[2],
    int c, int g)
{
  const float scale = 0.08838834764831845f;  // 1/sqrt(128)
  f32x4 zero4 = {0.f,0.f,0.f,0.f};

  // K fragments + inline copy (touch once, in registers); plain stores.
  s16x8 kf[2][4];
#pragma unroll
  for (int i = 0; i < 2; ++i){
    int row = l0 + i*16 + c;
    const float* src;
    if (FAST){
      src = Kpast + row*1024 + 8*g;
    } else {
      bool kn = ((unsigned)(row - pos)) < 8u;
      src = (kn ? KnewB : Kpast) + row*1024 + 8*g;
    }
    float* dst = Kout + row*1024 + 8*g;
#pragma unroll
    for (int ks = 0; ks < 4; ++ks){
      f32x4 x = *(const f32x4*)(src + ks*32);
      f32x4 y = *(const f32x4*)(src + ks*32 + 4);
      *(f32x4*)(dst + ks*32) = x;
      *(f32x4*)(dst + ks*32 + 4) = y;
      kf[i][ks] = cvt8(x, y);
    }
  }
  // scores: D[l][q] = K * Q^T
  f32x4 sc[2][2];
#pragma unroll
  for (int i = 0; i < 2; ++i)
#pragma unroll
    for (int j = 0; j < 2; ++j) sc[i][j] = zero4;
#pragma unroll
  for (int ks = 0; ks < 4; ++ks)
#pragma unroll
    for (int i = 0; i < 2; ++i)
#pragma unroll
      for (int j = 0; j < 2; ++j)
        sc[i][j] = __builtin_amdgcn_mfma_f32_16x16x32_bf16(kf[i][ks], qf[j][ks], sc[i][j], 0, 0, 0);

  // online softmax (per q column = lane c, tile j)
  float p[2][2][4];
  float fj[2];
#pragma unroll
  for (int j = 0; j < 2; ++j){
    const int qpos = ctx + ((j*16 + c) & 7);
    float mx = -1e30f;
#pragma unroll
    for (int i = 0; i < 2; ++i)
#pragma unroll
      for (int r = 0; r < 4; ++r){
        float v;
        if (FAST){
          v = sc[i][j][r] * scale;
        } else {
          int lg = l0 + i*16 + 4*g + r;
          v = (lg <= qpos) ? sc[i][j][r] * scale : -1e30f;
        }
        p[i][j][r] = v;
        mx = fmaxf(mx, v);
      }
    mx = fmaxf(mx, __shfl_xor(mx, 16));
    mx = fmaxf(mx, __shfl_xor(mx, 32));
    float mnew = fmaxf(m_j[j], mx);
    float f = __expf(m_j[j] - mnew);
    float lsum = 0.f;
#pragma unroll
    for (int i = 0; i < 2; ++i)
#pragma unroll
      for (int r = 0; r < 4; ++r){
        float pv;
        if (FAST){
          pv = __expf(p[i][j][r] - mnew);
        } else {
          int lg = l0 + i*16 + 4*g + r;
          pv = (lg <= qpos) ? __expf(p[i][j][r] - mnew) : 0.f;
        }
        p[i][j][r] = pv;
        lsum += pv;
      }
    s_j[j] = s_j[j] * f + lsum;
    m_j[j] = mnew;
    fj[j] = f;
  }
  // rescale O accumulators
#pragma unroll
  for (int iq = 0; iq < 2; ++iq)
#pragma unroll
    for (int r = 0; r < 4; ++r){
      float fo = __shfl(fj[iq], 4*g + r);
#pragma unroll
      for (int t = 0; t < 8; ++t) accO[iq][t][r] *= fo;
    }
  // relayout P into PV A-fragments: lane needs P[l=8g..8g+7][q=iq*16+c]
  s16x8 pf[2];
#pragma unroll
  for (int iq = 0; iq < 2; ++iq){
    int pd00 = (int)((unsigned)f2bf(p[0][iq][0]) | ((unsigned)f2bf(p[0][iq][1]) << 16));
    int pd01 = (int)((unsigned)f2bf(p[0][iq][2]) | ((unsigned)f2bf(p[0][iq][3]) << 16));
    int pd10 = (int)((unsigned)f2bf(p[1][iq][0]) | ((unsigned)f2bf(p[1][iq][1]) << 16));
    int pd11 = (int)((unsigned)f2bf(p[1][iq][2]) | ((unsigned)f2bf(p[1][iq][3]) << 16));
    int sA = (((2*g) & 3) << 4) | c;
    int sB = (((2*g + 1) & 3) << 4) | c;
    int h = g >> 1;
    int t0a = __shfl(pd00, sA), t1a = __shfl(pd10, sA);
    int t0b = __shfl(pd01, sA), t1b = __shfl(pd11, sA);
    int t0c = __shfl(pd00, sB), t1c = __shfl(pd10, sB);
    int t0d = __shfl(pd01, sB), t1d = __shfl(pd11, sB);
    int4 dw;
    dw.x = h ? t1a : t0a;
    dw.y = h ? t1b : t0b;
    dw.z = h ? t1c : t0c;
    dw.w = h ? t1d : t0d;
    pf[iq] = __builtin_bit_cast(s16x8, dw);
  }
  // V: fragment loads (+ element-wise copy to cache, PLAIN stores) + PV MFMA
#pragma unroll
  for (int t = 0; t < 8; ++t){
    const int co = t*16 + c;
    float vv[8];
#pragma unroll
    for (int jj = 0; jj < 8; ++jj){
      int row = l0 + 8*g + jj;
      float x;
      if (FAST){
        x = Vpast[row*1024 + co];
      } else {
        bool kn = ((unsigned)(row - pos)) < 8u;
        x = *((kn ? VnewB : Vpast) + row*1024 + co);
      }
      Vout[row*1024 + co] = x;          // plain store: L2 merges 64B granules
      vv[jj] = x;
    }
    f32x4 va, vb;
    va[0] = vv[0]; va[1] = vv[1]; va[2] = vv[2]; va[3] = vv[3];
    vb[0] = vv[4]; vb[1] = vv[5]; vb[2] = vv[6]; vb[3] = vv[7];
    s16x8 vf = cvt8(va, vb);
    accO[0][t] = __builtin_amdgcn_mfma_f32_16x16x32_bf16(pf[0], vf, accO[0][t], 0, 0, 0);
    accO[1][t] = __builtin_amdgcn_mfma_f32_16x16x32_bf16(pf[1], vf, accO[1][t], 0, 0, 0);
  }
}

// ---------------- fused cache-copy + flash attention, fine-grained blocks.
// grid: b*64 + hk*8 + sp (2048 blocks, 128 threads = 2 waves).
__global__ __launch_bounds__(128) void copy_attn(
    const float* __restrict__ past, const float* __restrict__ wskr,
    const float* __restrict__ wsvc, const unsigned short* __restrict__ qb,
    const int* __restrict__ ctxlen, const int* __restrict__ startv,
    float* __restrict__ cache,
    unsigned short* __restrict__ pO, float* __restrict__ pM, float* __restrict__ pS)
{
  const int bid = blockIdx.x;
  const int sp = bid & 7;
  const int hk = (bid >> 3) & 7;
  const int b  = bid >> 6;
  const int tid = threadIdx.x;
  const int w = tid >> 6;                // 0..1
  const int lane = tid & 63;
  const int c = lane & 15;
  const int g = lane >> 4;
  const int ctx = ctxlen[b];
  const int pos = startv[b];
  const int lbase = sp * 512;
  const int pid = bid * 2 + w;

  const float* Kpast = past + (size_t)b * 4194304 + hk * 128;
  const float* Vpast = Kpast + 134217728;
  float* Kout = cache + (size_t)b * 4194304 + hk * 128;
  float* Vout = Kout + 134217728;
  const float* KnewB = wskr + b * 8192 + hk * 128 - pos * 1024;
  const float* VnewB = wsvc + b * 8192 + hk * 128 - pos * 1024;

  // attention chunks in this 512-row slice
  int attLim = 0;
  {
    int t1 = ctx + 7 - lbase;
    if (t1 >= 0){ attLim = (t1 >> 5) + 1; if (attLim > 16) attLim = 16; }
  }

  f32x4 zero4 = {0.f,0.f,0.f,0.f};
  float m_j[2] = {-1e30f, -1e30f};
  float s_j[2] = {0.f, 0.f};

  const int rr = lane >> 5;
  const int fq = lane & 31;

  if (attLim > w){
    // Q fragments (B-operand): qf[jtile][kstep]
    s16x8 qf[2][4];
#pragma unroll
    for (int j = 0; j < 2; ++j){
      int r = j*16 + c; int s = r & 7; int gh = r >> 3;
      const unsigned short* qp = qb + (((b*8 + s) * 32) + hk*4 + gh) * 128 + 8*g;
#pragma unroll
      for (int ks = 0; ks < 4; ++ks)
        qf[j][ks] = __builtin_bit_cast(s16x8, *(const uint4*)(qp + ks*32));
    }

    f32x4 accO[2][8];
#pragma unroll
    for (int i = 0; i < 2; ++i)
#pragma unroll
      for (int t = 0; t < 8; ++t) accO[i][t] = zero4;

    for (int ci = w; ci < attLim; ci += 2){
      const int l0 = lbase + ci * 32;
      bool fullValid = (l0 + 31 <= ctx);
      bool hasNew = (l0 <= pos + 7) && (l0 + 31 >= pos);
      if (fullValid && !hasNew)
        attn_chunk<true >(l0, ctx, pos, Kpast, Vpast, KnewB, VnewB, Kout, Vout,
                          qf, accO, m_j, s_j, c, g);
      else
        attn_chunk<false>(l0, ctx, pos, Kpast, Vpast, KnewB, VnewB, Kout, Vout,
                          qf, accO, m_j, s_j, c, g);
    }
    // pO written only by waves that had chunks (bf16 partials)
#pragma unroll
    for (int iq = 0; iq < 2; ++iq)
#pragma unroll
      for (int t = 0; t < 8; ++t)
#pragma unroll
        for (int r = 0; r < 4; ++r)
          pO[(pid*32 + iq*16 + 4*g + r) * 128 + t*16 + c] = f2bf(accO[iq][t][r]);
  }

  // copy-only chunks (full-line streams: nontemporal both ways)
  int st2 = attLim + ((w - attLim) & 1);
  for (int ci = st2; ci < 16; ci += 2){
    const int l0 = lbase + ci * 32;
    bool inter = (l0 <= pos + 7) && (l0 + 31 >= pos);
    if (!inter){
#pragma unroll
      for (int j = 0; j < 16; ++j){
        int row = l0 + rr + 2*j;
        f32x4 kv = __builtin_nontemporal_load((const f32x4*)(Kpast + row*1024) + fq);
        f32x4 vv = __builtin_nontemporal_load((const f32x4*)(Vpast + row*1024) + fq);
        __builtin_nontemporal_store(kv, (f32x4*)(Kout + row*1024) + fq);
        __builtin_nontemporal_store(vv, (f32x4*)(Vout + row*1024) + fq);
      }
    } else {
      for (int j = 0; j < 16; ++j){
        int row = l0 + rr + 2*j;
        bool kn = ((unsigned)(row - pos)) < 8u;
        f32x4 kv = __builtin_nontemporal_load((const f32x4*)((kn ? KnewB : Kpast) + row*1024) + fq);
        f32x4 vv = __builtin_nontemporal_load((const f32x4*)((kn ? VnewB : Vpast) + row*1024) + fq);
        __builtin_nontemporal_store(kv, (f32x4*)(Kout + row*1024) + fq);
        __builtin_nontemporal_store(vv, (f32x4*)(Vout + row*1024) + fq);
      }
    }
  }

  // pM/pS always written (merge uses pS==0 to skip empty partials)
#pragma unroll
  for (int j = 0; j < 2; ++j){
    float sj = s_j[j];
    sj += __shfl_xor(sj, 16);
    sj += __shfl_xor(sj, 32);
    if (g == 0){
      pM[pid*32 + j*16 + c] = m_j[j];
      pS[pid*32 + j*16 + c] = sj;
    }
  }
}

// ---------------- merge 16 partials per (b,hk), skipping empty ones (bf16 pO)
__global__ __launch_bounds__(256) void merge_attn(const unsigned short* __restrict__ pO,
    const float* __restrict__ pM, const float* __restrict__ pS, float* __restrict__ attn)
{
  const int bh = blockIdx.x;             // b*8+hk
  const int b = bh >> 3, hk = bh & 7;
  const int tid = threadIdx.x;
  const int q = tid >> 3;                // 0..31
  const int d0 = (tid & 7) * 16;
  const int base = bh * 16;
  float eP[16], sv[16];
  float M = -1e30f;
#pragma unroll
  for (int p2 = 0; p2 < 16; ++p2){
    float m = pM[(base + p2) * 32 + q];
    eP[p2] = m;
    M = fmaxf(M, m);
  }
  float den = 0.f;
#pragma unroll
  for (int p2 = 0; p2 < 16; ++p2){
    float s_ = pS[(base + p2) * 32 + q];
    sv[p2] = s_;
    float e = __expf(eP[p2] - M);
    eP[p2] = e;
    den += e * s_;
  }
  float inv = 1.f / den;
  float a[16];
#pragma unroll
  for (int k2 = 0; k2 < 16; ++k2) a[k2] = 0.f;
#pragma unroll
  for (int p2 = 0; p2 < 16; ++p2){
    if (sv[p2] != 0.f){
      const unsigned short* src = pO + ((base + p2) * 32 + q) * 128 + d0;
      float e = eP[p2];
      uint4 w0 = *(const uint4*)(src);      // 8 bf16
      uint4 w1 = *(const uint4*)(src + 8);  // 8 bf16
      unsigned int wd[8] = {w0.x, w0.y, w0.z, w0.w, w1.x, w1.y, w1.z, w1.w};
#pragma unroll
      for (int k2 = 0; k2 < 8; ++k2){
        a[2*k2]   += e * bf2f(wd[k2] & 0xffffu);
        a[2*k2+1] += e * bf2f(wd[k2] >> 16);
      }
    }
  }
  const int gh = q >> 3, s = q & 7;
  float* o = attn + (b*8 + s) * 4096 + (hk*4 + gh) * 128 + d0;
#pragma unroll
  for (int k2 = 0; k2 < 16; ++k2) o[k2] = a[k2] * inv;
}

extern "C" void kernel_launch(void* const* d_in, const int* in_sizes, int n_in,
                              void* d_out, int out_size, void* d_ws, size_t ws_size,
                              hipStream_t stream) {
  const float* hidden = (const float*)d_in[0];
  const float* past   = (const float*)d_in[1];
  const float* rope   = (const float*)d_in[2];
  const int*   ctx    = (const int*)d_in[3];
  const int*   start  = (const int*)d_in[4];
  const float* Wq     = (const float*)d_in[5];
  const float* Wk     = (const float*)d_in[6];
  const float* Wv     = (const float*)d_in[7];
  const float* Wo     = (const float*)d_in[8];

  float* out_attn  = (float*)d_out;                 // (B,S,H) = 1048576 floats
  float* out_cache = out_attn + 1048576;            // (2,B,L,HK,D)

  float* ws = (float*)d_ws;
  float* qkv0   = ws;                               // 1572864 (split-K half 0)
  float* qkv1   = ws + 1572864;                     // 1572864 (split-K half 1)
  float* wsattn = ws + 3145728;                     // 1048576 (written by merge)
  float* wskr   = wsattn;                           // 262144 (aliased; dead before merge)
  float* wsvc   = wsattn + 262144;                  // 262144 (aliased; dead before merge)
  unsigned short* qb = (unsigned short*)(ws + 4194304); // 1048576 bf16 (= 524288 floats)
  float* obuf0  = ws + 4718592;                     // 1048576 (O-proj split-K half 0)
  float* obuf1  = ws + 5767168;                     // 1048576 (O-proj split-K half 1)
  unsigned short* pO = (unsigned short*)(ws + 6815744); // 4096*32*128 bf16 (= 8388608 floats)
  float* pM = ws + 15204352;                        // 4096 * 32
  float* pS = ws + 15335424;                        // 4096 * 32

  // fused QKV projection, split-K x2 (768 blocks)
  gemm_qkv<<<dim3(96, 4, 2), 256, 0, stream>>>(hidden, Wq, Wk, Wv, qkv0);

  // rope: sum split-K halves; q -> bf16, k roped, v compact
  rope_prep<<<256, 256, 0, stream>>>(qkv0, qkv1, rope, qb, wskr, wsvc);

  // fused cache copy + flash-decode attention, 2048 x 128-thread blocks
  copy_attn<<<2048, 128, 0, stream>>>(past, wskr, wsvc, qb, ctx, start,
                                      out_cache, pO, pM, pS);
  merge_attn<<<B_ * HK_, 256, 0, stream>>>(pO, pM, pS, wsattn);

  // output projection, split-K x2 (512 blocks) + reduce
  gemm_bt<<<dim3(64, 4, 2), 256, 0, stream>>>(wsattn, Wo, obuf0, 4096);
  add2<<<1024, 256, 0, stream>>>((const f32x4*)obuf0, (const f32x4*)obuf1,
                                 (f32x4*)out_attn);
}

// Round 14
// 584.390 us; speedup vs baseline: 2.1724x; 1.0018x over previous
//
#include <hip/hip_runtime.h>

#define B_ 32
#define S_ 8
#define H_ 4096
#define HQ_ 32
#define HK_ 8
#define D_ 128
#define L_ 4096
#define KK 4096
#define KQ 1024

typedef short s16x8 __attribute__((ext_vector_type(8)));
typedef float f32x4 __attribute__((ext_vector_type(4)));

// f32 -> bf16 bits, round-to-nearest-even (integer ALU; do NOT use inline-asm
// cvt_pk here -- R11: asm in the load chain breaks pipelining, 2x slowdown)
static __device__ __forceinline__ unsigned short f2bf(float x){
  unsigned int u = __builtin_bit_cast(unsigned int, x);
  u += 0x7fffu + ((u >> 16) & 1u);
  return (unsigned short)(u >> 16);
}

static __device__ __forceinline__ float bf2f(unsigned int h){
  unsigned int u = h << 16;
  return __builtin_bit_cast(float, u);
}

static __device__ __forceinline__ s16x8 cvt8(f32x4 a, f32x4 b){
  s16x8 r;
  r[0]=(short)f2bf(a[0]); r[1]=(short)f2bf(a[1]); r[2]=(short)f2bf(a[2]); r[3]=(short)f2bf(a[3]);
  r[4]=(short)f2bf(b[0]); r[5]=(short)f2bf(b[1]); r[6]=(short)f2bf(b[2]); r[7]=(short)f2bf(b[3]);
  return r;
}

// ---------------- fused QKV GEMM (BM=64, reg-pipelined, split-K x4)
// grid (96, 4, 4); z picks K-quarter; partials summed in rope_prep.
__global__ __launch_bounds__(256) void gemm_qkv(const float* __restrict__ A,
    const float* __restrict__ Wq, const float* __restrict__ Wk,
    const float* __restrict__ Wv, float* __restrict__ C)
{
  __shared__ short As[64][72];
  __shared__ short Bs[64][72];
  const int m0 = blockIdx.y * 64;
  const int n0 = blockIdx.x * 64;        // global col in [0,6144)
  const int k0 = blockIdx.z * KQ;
  float* Cz = C + blockIdx.z * 1572864;
  const float* W; int nw;
  if (n0 < 4096){ W = Wq; nw = n0; }
  else if (n0 < 5120){ W = Wk; nw = n0 - 4096; }
  else { W = Wv; nw = n0 - 5120; }
  const int tid = threadIdx.x;
  const int lane = tid & 63;
  const int w = tid >> 6;
  const int c = lane & 15;
  const int g = lane >> 4;
  const int wm = (w & 1) * 32;
  const int wn = (w >> 1) * 32;
  const int srow = tid >> 3;
  const int skc  = tid & 7;

  const float* Ar0 = A + (m0 + srow) * KK + skc * 8 + k0;
  const float* Ar1 = Ar0 + 32 * KK;
  const float* Wr0 = W + (nw + srow) * KK + skc * 8 + k0;
  const float* Wr1 = Wr0 + 32 * KK;

  f32x4 acc00 = {0.f,0.f,0.f,0.f};
  f32x4 acc01 = acc00, acc10 = acc00, acc11 = acc00;

  // preload tile 0 into registers
  f32x4 x0 = *(const f32x4*)(Ar0);
  f32x4 x1 = *(const f32x4*)(Ar0 + 4);
  f32x4 x2 = *(const f32x4*)(Ar1);
  f32x4 x3 = *(const f32x4*)(Ar1 + 4);
  f32x4 y0 = *(const f32x4*)(Wr0);
  f32x4 y1 = *(const f32x4*)(Wr0 + 4);
  f32x4 y2 = *(const f32x4*)(Wr1);
  f32x4 y3 = *(const f32x4*)(Wr1 + 4);

  for (int kt = 0; kt < KQ; kt += 64){
    __syncthreads();
    *(s16x8*)&As[srow][skc*8]    = cvt8(x0, x1);
    *(s16x8*)&As[srow+32][skc*8] = cvt8(x2, x3);
    *(s16x8*)&Bs[srow][skc*8]    = cvt8(y0, y1);
    *(s16x8*)&Bs[srow+32][skc*8] = cvt8(y2, y3);
    __syncthreads();
    // prefetch next tile (wraps on last iter; result unused)
    int ktn = (kt + 64) & (KQ - 1);
    x0 = *(const f32x4*)(Ar0 + ktn);
    x1 = *(const f32x4*)(Ar0 + ktn + 4);
    x2 = *(const f32x4*)(Ar1 + ktn);
    x3 = *(const f32x4*)(Ar1 + ktn + 4);
    y0 = *(const f32x4*)(Wr0 + ktn);
    y1 = *(const f32x4*)(Wr0 + ktn + 4);
    y2 = *(const f32x4*)(Wr1 + ktn);
    y3 = *(const f32x4*)(Wr1 + ktn + 4);
#pragma unroll
    for (int kk = 0; kk < 2; ++kk){
      s16x8 a0 = *(const s16x8*)&As[wm + c][kk*32 + 8*g];
      s16x8 a1 = *(const s16x8*)&As[wm + 16 + c][kk*32 + 8*g];
      s16x8 b0 = *(const s16x8*)&Bs[wn + c][kk*32 + 8*g];
      s16x8 b1 = *(const s16x8*)&Bs[wn + 16 + c][kk*32 + 8*g];
      acc00 = __builtin_amdgcn_mfma_f32_16x16x32_bf16(a0, b0, acc00, 0, 0, 0);
      acc01 = __builtin_amdgcn_mfma_f32_16x16x32_bf16(a0, b1, acc01, 0, 0, 0);
      acc10 = __builtin_amdgcn_mfma_f32_16x16x32_bf16(a1, b0, acc10, 0, 0, 0);
      acc11 = __builtin_amdgcn_mfma_f32_16x16x32_bf16(a1, b1, acc11, 0, 0, 0);
    }
  }
#pragma unroll
  for (int r = 0; r < 4; ++r){
    int row0 = m0 + wm + 4*g + r;
    int row1 = row0 + 16;
    int col0 = n0 + wn + c;
    int col1 = col0 + 16;
    Cz[row0 * 6144 + col0] = acc00[r];
    Cz[row0 * 6144 + col1] = acc01[r];
    Cz[row1 * 6144 + col0] = acc10[r];
    Cz[row1 * 6144 + col1] = acc11[r];
  }
}

// ---------------- O-proj GEMM (BM=64, reg-pipelined, split-K x4)
// grid (64, 4, 4); partials summed by add4.
__global__ __launch_bounds__(256) void gemm_bt(const float* __restrict__ A,
    const float* __restrict__ W, float* __restrict__ C, int N)
{
  __shared__ short As[64][72];
  __shared__ short Bs[64][72];
  const int m0 = blockIdx.y * 64;
  const int n0 = blockIdx.x * 64;
  const int k0 = blockIdx.z * KQ;
  float* Cz = C + blockIdx.z * 1048576;
  const int tid = threadIdx.x;
  const int lane = tid & 63;
  const int w = tid >> 6;
  const int c = lane & 15;
  const int g = lane >> 4;
  const int wm = (w & 1) * 32;
  const int wn = (w >> 1) * 32;
  const int srow = tid >> 3;
  const int skc  = tid & 7;

  const float* Ar0 = A + (m0 + srow) * KK + skc * 8 + k0;
  const float* Ar1 = Ar0 + 32 * KK;
  const float* Wr0 = W + (n0 + srow) * KK + skc * 8 + k0;
  const float* Wr1 = Wr0 + 32 * KK;

  f32x4 acc00 = {0.f,0.f,0.f,0.f};
  f32x4 acc01 = acc00, acc10 = acc00, acc11 = acc00;

  f32x4 x0 = *(const f32x4*)(Ar0);
  f32x4 x1 = *(const f32x4*)(Ar0 + 4);
  f32x4 x2 = *(const f32x4*)(Ar1);
  f32x4 x3 = *(const f32x4*)(Ar1 + 4);
  f32x4 y0 = *(const f32x4*)(Wr0);
  f32x4 y1 = *(const f32x4*)(Wr0 + 4);
  f32x4 y2 = *(const f32x4*)(Wr1);
  f32x4 y3 = *(const f32x4*)(Wr1 + 4);

  for (int kt = 0; kt < KQ; kt += 64){
    __syncthreads();
    *(s16x8*)&As[srow][skc*8]    = cvt8(x0, x1);
    *(s16x8*)&As[srow+32][skc*8] = cvt8(x2, x3);
    *(s16x8*)&Bs[srow][skc*8]    = cvt8(y0, y1);
    *(s16x8*)&Bs[srow+32][skc*8] = cvt8(y2, y3);
    __syncthreads();
    int ktn = (kt + 64) & (KQ - 1);
    x0 = *(const f32x4*)(Ar0 + ktn);
    x1 = *(const f32x4*)(Ar0 + ktn + 4);
    x2 = *(const f32x4*)(Ar1 + ktn);
    x3 = *(const f32x4*)(Ar1 + ktn + 4);
    y0 = *(const f32x4*)(Wr0 + ktn);
    y1 = *(const f32x4*)(Wr0 + ktn + 4);
    y2 = *(const f32x4*)(Wr1 + ktn);
    y3 = *(const f32x4*)(Wr1 + ktn + 4);
#pragma unroll
    for (int kk = 0; kk < 2; ++kk){
      s16x8 a0 = *(const s16x8*)&As[wm + c][kk*32 + 8*g];
      s16x8 a1 = *(const s16x8*)&As[wm + 16 + c][kk*32 + 8*g];
      s16x8 b0 = *(const s16x8*)&Bs[wn + c][kk*32 + 8*g];
      s16x8 b1 = *(const s16x8*)&Bs[wn + 16 + c][kk*32 + 8*g];
      acc00 = __builtin_amdgcn_mfma_f32_16x16x32_bf16(a0, b0, acc00, 0, 0, 0);
      acc01 = __builtin_amdgcn_mfma_f32_16x16x32_bf16(a0, b1, acc01, 0, 0, 0);
      acc10 = __builtin_amdgcn_mfma_f32_16x16x32_bf16(a1, b0, acc10, 0, 0, 0);
      acc11 = __builtin_amdgcn_mfma_f32_16x16x32_bf16(a1, b1, acc11, 0, 0, 0);
    }
  }
#pragma unroll
  for (int r = 0; r < 4; ++r){
    int row0 = m0 + wm + 4*g + r;
    int row1 = row0 + 16;
    int col0 = n0 + wn + c;
    int col1 = col0 + 16;
    Cz[row0 * N + col0] = acc00[r];
    Cz[row0 * N + col1] = acc01[r];
    Cz[row1 * N + col0] = acc10[r];
    Cz[row1 * N + col1] = acc11[r];
  }
}

// ---------------- sum four split-K partials into d_out
__global__ __launch_bounds__(256) void add4(const f32x4* __restrict__ a,
    const f32x4* __restrict__ b, const f32x4* __restrict__ cc,
    const f32x4* __restrict__ d, f32x4* __restrict__ o)
{
  int i = blockIdx.x * 256 + threadIdx.x;   // 262144 f32x4 total, grid 1024
  o[i] = (a[i] + b[i]) + (cc[i] + d[i]);
}

// ---------------- RoPE: sums split-K qkv quarters; q -> bf16 qb; k -> wskr; v -> wsvc
__global__ __launch_bounds__(256) void rope_prep(
    const float* __restrict__ qkv0, const float* __restrict__ rope,
    unsigned short* __restrict__ qbuf, float* __restrict__ wskr, float* __restrict__ wsvc)
{
  const int bs = blockIdx.x;            // b*8+s
  const int tid = threadIdx.x;
  const float* cosv = rope + bs * 128;
  const float* sinv = cosv + 64;
  const float* row0 = qkv0 + bs * 6144;
  const float* row1 = row0 + 1572864;
  const float* row2 = row0 + 3145728;
  const float* row3 = row0 + 4718592;
#pragma unroll
  for (int it = 0; it < 16; ++it){
    int e = tid + it * 256;             // over HQ*D = 4096
    int d = e & 127; int dh = d & 63;
    float x  = (row0[e] + row1[e]) + (row2[e] + row3[e]);
    int ep = e ^ 64;
    float xp = (row0[ep] + row1[ep]) + (row2[ep] + row3[ep]);
    float o = (d < 64) ? (x * cosv[dh] - xp * sinv[dh]) : (x * cosv[dh] + xp * sinv[dh]);
    qbuf[bs*4096 + e] = f2bf(o);
  }
#pragma unroll
  for (int it = 0; it < 4; ++it){
    int e = tid + it * 256;             // over HK*D = 1024
    int d = e & 127; int dh = d & 63;
    int e4 = 4096 + e, e4p = 4096 + (e ^ 64), e5 = 5120 + e;
    float x  = (row0[e4] + row1[e4]) + (row2[e4] + row3[e4]);
    float xp = (row0[e4p] + row1[e4p]) + (row2[e4p] + row3[e4p]);
    float o = (d < 64) ? (x * cosv[dh] - xp * sinv[dh]) : (x * cosv[dh] + xp * sinv[dh]);
    wskr[bs*1024 + e] = o;
    wsvc[bs*1024 + e] = (row0[e5] + row1[e5]) + (row2[e5] + row3[e5]);
  }
}

// ---------------- per-chunk attention+copy body.
// FAST: chunk fully below ctx and contains no new rows.
// ALL copy stores on the attention path are PLAIN (partial-line NT stores
// defeat L2 write-merging -- validated R9: V NT->plain was -47us).
template<bool FAST>
static __device__ __forceinline__ void attn_chunk(
    int l0, int ctx, int pos,
    const float* __restrict__ Kpast, const float* __restrict__ Vpast,
    const float* __restrict__ KnewB, const float* __restrict__ VnewB,
    float* __restrict__ Kout, float* __restrict__ Vout,
    const s16x8 (&qf)[2][4], f32x4 (&accO)[2][8],
    float (&m_j)[2], float (&s_j)[2],
    int c, int g)
{
  const float scale = 0.08838834764831845f;  // 1/sqrt(128)
  f32x4 zero4 = {0.f,0.f,0.f,0.f};

  // K fragments + inline copy (touch once, in registers); plain stores.
  s16x8 kf[2][4];
#pragma unroll
  for (int i = 0; i < 2; ++i){
    int row = l0 + i*16 + c;
    const float* src;
    if (FAST){
      src = Kpast + row*1024 + 8*g;
    } else {
      bool kn = ((unsigned)(row - pos)) < 8u;
      src = (kn ? KnewB : Kpast) + row*1024 + 8*g;
    }
    float* dst = Kout + row*1024 + 8*g;
#pragma unroll
    for (int ks = 0; ks < 4; ++ks){
      f32x4 x = *(const f32x4*)(src + ks*32);
      f32x4 y = *(const f32x4*)(src + ks*32 + 4);
      *(f32x4*)(dst + ks*32) = x;
      *(f32x4*)(dst + ks*32 + 4) = y;
      kf[i][ks] = cvt8(x, y);
    }
  }
  // scores: D[l][q] = K * Q^T
  f32x4 sc[2][2];
#pragma unroll
  for (int i = 0; i < 2; ++i)
#pragma unroll
    for (int j = 0; j < 2; ++j) sc[i][j] = zero4;
#pragma unroll
  for (int ks = 0; ks < 4; ++ks)
#pragma unroll
    for (int i = 0; i < 2; ++i)
#pragma unroll
      for (int j = 0; j < 2; ++j)
        sc[i][j] = __builtin_amdgcn_mfma_f32_16x16x32_bf16(kf[i][ks], qf[j][ks], sc[i][j], 0, 0, 0);

  // online softmax (per q column = lane c, tile j)
  float p[2][2][4];
  float fj[2];
#pragma unroll
  for (int j = 0; j < 2; ++j){
    const int qpos = ctx + ((j*16 + c) & 7);
    float mx = -1e30f;
#pragma unroll
    for (int i = 0; i < 2; ++i)
#pragma unroll
      for (int r = 0; r < 4; ++r){
        float v;
        if (FAST){
          v = sc[i][j][r] * scale;
        } else {
          int lg = l0 + i*16 + 4*g + r;
          v = (lg <= qpos) ? sc[i][j][r] * scale : -1e30f;
        }
        p[i][j][r] = v;
        mx = fmaxf(mx, v);
      }
    mx = fmaxf(mx, __shfl_xor(mx, 16));
    mx = fmaxf(mx, __shfl_xor(mx, 32));
    float mnew = fmaxf(m_j[j], mx);
    float f = __expf(m_j[j] - mnew);
    float lsum = 0.f;
#pragma unroll
    for (int i = 0; i < 2; ++i)
#pragma unroll
      for (int r = 0; r < 4; ++r){
        float pv;
        if (FAST){
          pv = __expf(p[i][j][r] - mnew);
        } else {
          int lg = l0 + i*16 + 4*g + r;
          pv = (lg <= qpos) ? __expf(p[i][j][r] - mnew) : 0.f;
        }
        p[i][j][r] = pv;
        lsum += pv;
      }
    s_j[j] = s_j[j] * f + lsum;
    m_j[j] = mnew;
    fj[j] = f;
  }
  // rescale O accumulators -- skipped when no lane's max advanced (f==1):
  // wave-uniform branch via __all; bit-exact (multiply-by-1 elided).
  if (!(__all(fj[0] == 1.f) && __all(fj[1] == 1.f))){
#pragma unroll
    for (int iq = 0; iq < 2; ++iq)
#pragma unroll
      for (int r = 0; r < 4; ++r){
        float fo = __shfl(fj[iq], 4*g + r);
#pragma unroll
        for (int t = 0; t < 8; ++t) accO[iq][t][r] *= fo;
      }
  }
  // relayout P into PV A-fragments: lane needs P[l=8g..8g+7][q=iq*16+c]
  s16x8 pf[2];
#pragma unroll
  for (int iq = 0; iq < 2; ++iq){
    int pd00 = (int)((unsigned)f2bf(p[0][iq][0]) | ((unsigned)f2bf(p[0][iq][1]) << 16));
    int pd01 = (int)((unsigned)f2bf(p[0][iq][2]) | ((unsigned)f2bf(p[0][iq][3]) << 16));
    int pd10 = (int)((unsigned)f2bf(p[1][iq][0]) | ((unsigned)f2bf(p[1][iq][1]) << 16));
    int pd11 = (int)((unsigned)f2bf(p[1][iq][2]) | ((unsigned)f2bf(p[1][iq][3]) << 16));
    int sA = (((2*g) & 3) << 4) | c;
    int sB = (((2*g + 1) & 3) << 4) | c;
    int h = g >> 1;
    int t0a = __shfl(pd00, sA), t1a = __shfl(pd10, sA);
    int t0b = __shfl(pd01, sA), t1b = __shfl(pd11, sA);
    int t0c = __shfl(pd00, sB), t1c = __shfl(pd10, sB);
    int t0d = __shfl(pd01, sB), t1d = __shfl(pd11, sB);
    int4 dw;
    dw.x = h ? t1a : t0a;
    dw.y = h ? t1b : t0b;
    dw.z = h ? t1c : t0c;
    dw.w = h ? t1d : t0d;
    pf[iq] = __builtin_bit_cast(s16x8, dw);
  }
  // V: fragment loads (+ element-wise copy to cache, PLAIN stores) + PV MFMA
#pragma unroll
  for (int t = 0; t < 8; ++t){
    const int co = t*16 + c;
    float vv[8];
#pragma unroll
    for (int jj = 0; jj < 8; ++jj){
      int row = l0 + 8*g + jj;
      float x;
      if (FAST){
        x = Vpast[row*1024 + co];
      } else {
        bool kn = ((unsigned)(row - pos)) < 8u;
        x = *((kn ? VnewB : Vpast) + row*1024 + co);
      }
      Vout[row*1024 + co] = x;          // plain store: L2 merges 64B granules
      vv[jj] = x;
    }
    f32x4 va, vb;
    va[0] = vv[0]; va[1] = vv[1]; va[2] = vv[2]; va[3] = vv[3];
    vb[0] = vv[4]; vb[1] = vv[5]; vb[2] = vv[6]; vb[3] = vv[7];
    s16x8 vf = cvt8(va, vb);
    accO[0][t] = __builtin_amdgcn_mfma_f32_16x16x32_bf16(pf[0], vf, accO[0][t], 0, 0, 0);
    accO[1][t] = __builtin_amdgcn_mfma_f32_16x16x32_bf16(pf[1], vf, accO[1][t], 0, 0, 0);
  }
}

// ---------------- fused cache-copy + flash attention, fine-grained blocks.
// grid: b*64 + hk*8 + sp (2048 blocks, 128 threads = 2 waves).
__global__ __launch_bounds__(128) void copy_attn(
    const float* __restrict__ past, const float* __restrict__ wskr,
    const float* __restrict__ wsvc, const unsigned short* __restrict__ qb,
    const int* __restrict__ ctxlen, const int* __restrict__ startv,
    float* __restrict__ cache,
    unsigned short* __restrict__ pO, float* __restrict__ pM, float* __restrict__ pS)
{
  const int bid = blockIdx.x;
  const int sp = bid & 7;
  const int hk = (bid >> 3) & 7;
  const int b  = bid >> 6;
  const int tid = threadIdx.x;
  const int w = tid >> 6;                // 0..1
  const int lane = tid & 63;
  const int c = lane & 15;
  const int g = lane >> 4;
  const int ctx = ctxlen[b];
  const int pos = startv[b];
  const int lbase = sp * 512;
  const int pid = bid * 2 + w;

  const float* Kpast = past + (size_t)b * 4194304 + hk * 128;
  const float* Vpast = Kpast + 134217728;
  float* Kout = cache + (size_t)b * 4194304 + hk * 128;
  float* Vout = Kout + 134217728;
  const float* KnewB = wskr + b * 8192 + hk * 128 - pos * 1024;
  const float* VnewB = wsvc + b * 8192 + hk * 128 - pos * 1024;

  // attention chunks in this 512-row slice
  int attLim = 0;
  {
    int t1 = ctx + 7 - lbase;
    if (t1 >= 0){ attLim = (t1 >> 5) + 1; if (attLim > 16) attLim = 16; }
  }

  f32x4 zero4 = {0.f,0.f,0.f,0.f};
  float m_j[2] = {-1e30f, -1e30f};
  float s_j[2] = {0.f, 0.f};

  const int rr = lane >> 5;
  const int fq = lane & 31;

  if (attLim > w){
    // Q fragments (B-operand): qf[jtile][kstep]
    s16x8 qf[2][4];
#pragma unroll
    for (int j = 0; j < 2; ++j){
      int r = j*16 + c; int s = r & 7; int gh = r >> 3;
      const unsigned short* qp = qb + (((b*8 + s) * 32) + hk*4 + gh) * 128 + 8*g;
#pragma unroll
      for (int ks = 0; ks < 4; ++ks)
        qf[j][ks] = __builtin_bit_cast(s16x8, *(const uint4*)(qp + ks*32));
    }

    f32x4 accO[2][8];
#pragma unroll
    for (int i = 0; i < 2; ++i)
#pragma unroll
      for (int t = 0; t < 8; ++t) accO[i][t] = zero4;

    for (int ci = w; ci < attLim; ci += 2){
      const int l0 = lbase + ci * 32;
      bool fullValid = (l0 + 31 <= ctx);
      bool hasNew = (l0 <= pos + 7) && (l0 + 31 >= pos);
      if (fullValid && !hasNew)
        attn_chunk<true >(l0, ctx, pos, Kpast, Vpast, KnewB, VnewB, Kout, Vout,
                          qf, accO, m_j, s_j, c, g);
      else
        attn_chunk<false>(l0, ctx, pos, Kpast, Vpast, KnewB, VnewB, Kout, Vout,
                          qf, accO, m_j, s_j, c, g);
    }
    // pO written only by waves that had chunks (bf16 partials)
#pragma unroll
    for (int iq = 0; iq < 2; ++iq)
#pragma unroll
      for (int t = 0; t < 8; ++t)
#pragma unroll
        for (int r = 0; r < 4; ++r)
          pO[(pid*32 + iq*16 + 4*g + r) * 128 + t*16 + c] = f2bf(accO[iq][t][r]);
  }

  // copy-only chunks (full-line streams: nontemporal both ways)
  int st2 = attLim + ((w - attLim) & 1);
  for (int ci = st2; ci < 16; ci += 2){
    const int l0 = lbase + ci * 32;
    bool inter = (l0 <= pos + 7) && (l0 + 31 >= pos);
    if (!inter){
#pragma unroll
      for (int j = 0; j < 16; ++j){
        int row = l0 + rr + 2*j;
        f32x4 kv = __builtin_nontemporal_load((const f32x4*)(Kpast + row*1024) + fq);
        f32x4 vv = __builtin_nontemporal_load((const f32x4*)(Vpast + row*1024) + fq);
        __builtin_nontemporal_store(kv, (f32x4*)(Kout + row*1024) + fq);
        __builtin_nontemporal_store(vv, (f32x4*)(Vout + row*1024) + fq);
      }
    } else {
      for (int j = 0; j < 16; ++j){
        int row = l0 + rr + 2*j;
        bool kn = ((unsigned)(row - pos)) < 8u;
        f32x4 kv = __builtin_nontemporal_load((const f32x4*)((kn ? KnewB : Kpast) + row*1024) + fq);
        f32x4 vv = __builtin_nontemporal_load((const f32x4*)((kn ? VnewB : Vpast) + row*1024) + fq);
        __builtin_nontemporal_store(kv, (f32x4*)(Kout + row*1024) + fq);
        __builtin_nontemporal_store(vv, (f32x4*)(Vout + row*1024) + fq);
      }
    }
  }

  // pM/pS always written (merge uses pS==0 to skip empty partials)
#pragma unroll
  for (int j = 0; j < 2; ++j){
    float sj = s_j[j];
    sj += __shfl_xor(sj, 16);
    sj += __shfl_xor(sj, 32);
    if (g == 0){
      pM[pid*32 + j*16 + c] = m_j[j];
      pS[pid*32 + j*16 + c] = sj;
    }
  }
}

// ---------------- merge 16 partials per (b,hk), skipping empty ones (bf16 pO)
__global__ __launch_bounds__(256) void merge_attn(const unsigned short* __restrict__ pO,
    const float* __restrict__ pM, const float* __restrict__ pS, float* __restrict__ attn)
{
  const int bh = blockIdx.x;             // b*8+hk
  const int b = bh >> 3, hk = bh & 7;
  const int tid = threadIdx.x;
  const int q = tid >> 3;                // 0..31
  const int d0 = (tid & 7) * 16;
  const int base = bh * 16;
  float eP[16], sv[16];
  float M = -1e30f;
#pragma unroll
  for (int p2 = 0; p2 < 16; ++p2){
    float m = pM[(base + p2) * 32 + q];
    eP[p2] = m;
    M = fmaxf(M, m);
  }
  float den = 0.f;
#pragma unroll
  for (int p2 = 0; p2 < 16; ++p2){
    float s_ = pS[(base + p2) * 32 + q];
    sv[p2] = s_;
    float e = __expf(eP[p2] - M);
    eP[p2] = e;
    den += e * s_;
  }
  float inv = 1.f / den;
  float a[16];
#pragma unroll
  for (int k2 = 0; k2 < 16; ++k2) a[k2] = 0.f;
#pragma unroll
  for (int p2 = 0; p2 < 16; ++p2){
    if (sv[p2] != 0.f){
      const unsigned short* src = pO + ((base + p2) * 32 + q) * 128 + d0;
      float e = eP[p2];
      uint4 w0 = *(const uint4*)(src);      // 8 bf16
      uint4 w1 = *(const uint4*)(src + 8);  // 8 bf16
      unsigned int wd[8] = {w0.x, w0.y, w0.z, w0.w, w1.x, w1.y, w1.z, w1.w};
#pragma unroll
      for (int k2 = 0; k2 < 8; ++k2){
        a[2*k2]   += e * bf2f(wd[k2] & 0xffffu);
        a[2*k2+1] += e * bf2f(wd[k2] >> 16);
      }
    }
  }
  const int gh = q >> 3, s = q & 7;
  float* o = attn + (b*8 + s) * 4096 + (hk*4 + gh) * 128 + d0;
#pragma unroll
  for (int k2 = 0; k2 < 16; ++k2) o[k2] = a[k2] * inv;
}

extern "C" void kernel_launch(void* const* d_in, const int* in_sizes, int n_in,
                              void* d_out, int out_size, void* d_ws, size_t ws_size,
                              hipStream_t stream) {
  const float* hidden = (const float*)d_in[0];
  const float* past   = (const float*)d_in[1];
  const float* rope   = (const float*)d_in[2];
  const int*   ctx    = (const int*)d_in[3];
  const int*   start  = (const int*)d_in[4];
  const float* Wq     = (const float*)d_in[5];
  const float* Wk     = (const float*)d_in[6];
  const float* Wv     = (const float*)d_in[7];
  const float* Wo     = (const float*)d_in[8];

  float* out_attn  = (float*)d_out;                 // (B,S,H) = 1048576 floats
  float* out_cache = out_attn + 1048576;            // (2,B,L,HK,D)

  // Workspace map (floats; end offsets verified):
  //   [0,        6291456)  qkv quarters   (gemm_qkv -> rope_prep)
  //   [0,        8388608)  pO bf16        (copy_attn -> merge; REUSES qkv region)
  //   [8388608,  9437184)  wsattn         (merge -> gemm_bt); wskr/wsvc alias front
  //   [9437184,  9961472)  qb bf16        (rope -> copy_attn)
  //   [9961472, 10092544)  pM             (copy_attn -> merge)
  //   [10092544,10223616)  pS             (copy_attn -> merge)
  //   [10223616,14417920)  obuf           (gemm_bt -> add4)
  float* ws = (float*)d_ws;
  float* qkv0   = ws;
  unsigned short* pO = (unsigned short*)ws;
  float* wsattn = ws + 8388608;
  float* wskr   = wsattn;
  float* wsvc   = wsattn + 262144;
  unsigned short* qb = (unsigned short*)(ws + 9437184);
  float* pM   = ws + 9961472;
  float* pS   = ws + 10092544;
  float* obuf = ws + 10223616;

  // fused QKV projection, split-K x4 (1536 blocks)
  gemm_qkv<<<dim3(96, 4, 4), 256, 0, stream>>>(hidden, Wq, Wk, Wv, qkv0);

  // rope: sum split-K quarters; q -> bf16, k roped, v compact
  rope_prep<<<256, 256, 0, stream>>>(qkv0, rope, qb, wskr, wsvc);

  // fused cache copy + flash-decode attention, 2048 x 128-thread blocks
  copy_attn<<<2048, 128, 0, stream>>>(past, wskr, wsvc, qb, ctx, start,
                                      out_cache, pO, pM, pS);
  merge_attn<<<B_ * HK_, 256, 0, stream>>>(pO, pM, pS, wsattn);

  // output projection, split-K x4 (1024 blocks) + reduce
  gemm_bt<<<dim3(64, 4, 4), 256, 0, stream>>>(wsattn, Wo, obuf, 4096);
  add4<<<1024, 256, 0, stream>>>((const f32x4*)obuf,
                                 (const f32x4*)(obuf + 1048576),
                                 (const f32x4*)(obuf + 2097152),
                                 (const f32x4*)(obuf + 3145728),
                                 (f32x4*)out_attn);
}